// Round 7
// baseline (219.972 us; speedup 1.0000x reference)
//
#include <hip/hip_runtime.h>

#define D_DIM 1024
#define NROWS 8192

typedef float f32x4 __attribute__((ext_vector_type(4)));
typedef long  i64x2 __attribute__((ext_vector_type(2)));

typedef const __attribute__((address_space(1))) void* gaddr_t;
typedef __attribute__((address_space(3))) void* laddr_t;

__device__ __forceinline__ void load16_to_lds(const void* g, void* l) {
    __builtin_amdgcn_global_load_lds((gaddr_t)g, (laddr_t)l, 16, 0, 0);
}

// ---- kernel 1: fp32 row-normalize -> fp8 e4m3, one WAVE per row (no barriers).
// K is PERMUTED within each 64-element block (identically for A and B — dot
// products are K-permutation-invariant) so each GEMM lane's fragment for MFMA
// steps 0,1 is one contiguous 16-B read: orig k = 32s+8f+b (s=step 0..1,
// f=lane quarter 0..3, b=0..7) stored at byte f*16 + s*8 + b of the block.
// Writes stay within their 64-B half-line -> coalesced. Also zeroes the
// encoded-max array (ws is poisoned 0xAA each call).
__global__ __launch_bounds__(256) void normalize_rows(const float* __restrict__ ex,
                                                      const float* __restrict__ ey,
                                                      unsigned char* __restrict__ Aq,
                                                      unsigned char* __restrict__ Bq,
                                                      int* __restrict__ maxenc) {
    const int wave = threadIdx.x >> 6, lane = threadIdx.x & 63;
    const int r = blockIdx.x * 4 + wave;
    if (lane == 0) maxenc[r] = 0;   // 0 < int-encoding of any (cosine+2.0) > 0

    const float* src;
    unsigned char* dst;
    if (r < NROWS) { src = ex + (size_t)r * D_DIM;           dst = Aq + (size_t)r * D_DIM; }
    else           { src = ey + (size_t)(r - NROWS) * D_DIM; dst = Bq + (size_t)(r - NROWS) * D_DIM; }

    float4 v[4];
    float ss = 0.0f;
    #pragma unroll
    for (int j = 0; j < 4; ++j) {
        v[j] = ((const float4*)src)[lane + 64 * j];
        ss += v[j].x * v[j].x + v[j].y * v[j].y + v[j].z * v[j].z + v[j].w * v[j].w;
    }
    #pragma unroll
    for (int off = 32; off; off >>= 1) ss += __shfl_xor(ss, off, 64);
    float scale = 1.0f / fmaxf(sqrtf(ss), 1e-8f);

    #pragma unroll
    for (int j = 0; j < 4; ++j) {
        int p = (lane + 64 * j) << 2;          // orig byte index of this 4-pack
        int blk = p >> 6, w = p & 63;
        int s = w >> 5, f = (w >> 3) & 3, b = w & 7;
        int q = blk * 64 + f * 16 + s * 8 + b;
        int pk = 0;   // v_cvt_pk_fp8_f32: RNE, saturating; |x| <= ~0.3, no overflow
        pk = __builtin_amdgcn_cvt_pk_fp8_f32(v[j].x * scale, v[j].y * scale, pk, false);
        pk = __builtin_amdgcn_cvt_pk_fp8_f32(v[j].z * scale, v[j].w * scale, pk, true);
        ((int*)dst)[q >> 2] = pk;
    }
}

// ---- kernel 2: 128x128-tile fp8 MFMA GEMM (C = A . B^T) with fused row/col max.
// R7 vs R6: single-barrier double-buffered K-loop. BK=64 -> each 16-KB stage
// (A 8K + B 8K) fits twice in 32 KB LDS (occupancy unchanged). Loads for tile
// kt+1 are issued BEFORE tile kt's MFMA block, so the compiler's pre-barrier
// vmcnt(0) drain waits on loads that aged the whole MFMA phase (~1500 cyc) —
// the R6 structure drained fresh loads instead (its ~55% stall).
// LDS: row = 64 B = 4 chunks of 16 B, chunk c of row r at pos c ^ ((r>>1)&3)
// (row stride = 16 banks, so even/odd rows split bank halves; r>>1 decorrelates
// — each 8-lane b128 phase covers all 32 banks exactly once, conflict-free).
// With the 64-block K-permutation each lane's per-kt fragment is ONE
// ds_read_b128 = i64x2 = MFMA steps 0,1.
__global__ __launch_bounds__(256) void gemm_max(const unsigned char* __restrict__ A,
                                                const unsigned char* __restrict__ B,
                                                int* __restrict__ rowmax,
                                                int* __restrict__ colmax) {
    __shared__ __align__(16) unsigned char Lds[2][16384];   // [buf][A 8K | B 8K]

    const int bm = blockIdx.x >> 6;
    const int bn = blockIdx.x & 63;
    const int rowb = bm * 128;
    const int colb = bn * 128;

    const int t    = threadIdx.x;
    const int lane = t & 63;
    const int wave = t >> 6;
    const int wm = (wave & 1) * 64;       // wave row offset within tile
    const int wn = (wave >> 1) * 64;      // wave col offset within tile
    const int fr = lane & 15;             // fragment row/col index
    const int fq = lane >> 4;             // quarter: frag k-bytes 8*fq per step
    // fragment read position (i-independent: (wm+i*16+fr)>>1 & 3 == (fr>>1)&3)
    const int fpos = (fq ^ ((fr >> 1) & 3)) * 16;

    // staging: wave w stages rows [16w,16w+16) and [64+16w,64+16w+16) of A and B;
    // lane l covers row base+(l>>2), chunk position l&3 (LDS dest = wave-uniform
    // base + lane*16). Global source chunk = pos ^ ((row>>1)&3).
    const int srow1 = wave * 16 + (lane >> 2);
    const int srow2 = 64 + srow1;
    const int spos = lane & 3;
    const int c1 = (spos ^ ((srow1 >> 1) & 3)) * 16;
    const int c2 = (spos ^ ((srow2 >> 1) & 3)) * 16;

    const unsigned char* Ag1 = A + (size_t)(rowb + srow1) * D_DIM + c1;
    const unsigned char* Ag2 = A + (size_t)(rowb + srow2) * D_DIM + c2;
    const unsigned char* Bg1 = B + (size_t)(colb + srow1) * D_DIM + c1;
    const unsigned char* Bg2 = B + (size_t)(colb + srow2) * D_DIM + c2;

    f32x4 acc[4][4] = {};

    // prologue: stage kt=0 into buffer 0
    {
        unsigned char* d = &Lds[0][0] + wave * 1024;
        load16_to_lds(Ag1, d);
        load16_to_lds(Ag2, d + 4096);
        load16_to_lds(Bg1, d + 8192);
        load16_to_lds(Bg2, d + 12288);
    }
    __syncthreads();

    #pragma unroll 2
    for (int kt = 0; kt < 16; ++kt) {
        // issue next tile's loads FIRST — they stay in flight during the MFMAs
        if (kt < 15) {
            const int ko = (kt + 1) * 64;
            unsigned char* d = &Lds[(kt + 1) & 1][0] + wave * 1024;
            load16_to_lds(Ag1 + ko, d);
            load16_to_lds(Ag2 + ko, d + 4096);
            load16_to_lds(Bg1 + ko, d + 8192);
            load16_to_lds(Bg2 + ko, d + 12288);
        }

        const unsigned char* Ab = &Lds[kt & 1][0];
        const unsigned char* Bb = Ab + 8192;

        i64x2 av[4];
        #pragma unroll
        for (int i = 0; i < 4; ++i)
            av[i] = *(const i64x2*)(Ab + (wm + i * 16 + fr) * 64 + fpos);
        #pragma unroll
        for (int j = 0; j < 4; ++j) {
            i64x2 bv = *(const i64x2*)(Bb + (wn + j * 16 + fr) * 64 + fpos);
            #pragma unroll
            for (int i = 0; i < 4; ++i) {
                acc[i][j] = __builtin_amdgcn_mfma_f32_16x16x32_fp8_fp8(av[i][0], bv[0], acc[i][j], 0, 0, 0);
                acc[i][j] = __builtin_amdgcn_mfma_f32_16x16x32_fp8_fp8(av[i][1], bv[1], acc[i][j], 0, 0, 0);
            }
        }
        __syncthreads();   // drains vmcnt for kt+1's (aged) loads + releases buffers
    }

    // ---- epilogue: fused max reductions.
    // C/D layout (shape-determined, m89-verified): col = lane&15, row = fq*4 + reg.
    const float SH = 2.0f;   // cosine >= -1 -> v+2 > 0 -> int-ordered float bits

    #pragma unroll
    for (int i = 0; i < 4; ++i) {
        #pragma unroll
        for (int r = 0; r < 4; ++r) {
            float m = fmaxf(fmaxf(acc[i][0][r], acc[i][1][r]),
                            fmaxf(acc[i][2][r], acc[i][3][r]));
            m = fmaxf(m, __shfl_xor(m, 1, 64));   // reduce over the 16 lanes sharing fq
            m = fmaxf(m, __shfl_xor(m, 2, 64));
            m = fmaxf(m, __shfl_xor(m, 4, 64));
            m = fmaxf(m, __shfl_xor(m, 8, 64));
            if (fr == 0) {
                int row = rowb + wm + i * 16 + fq * 4 + r;
                atomicMax(&rowmax[row], __float_as_int(m + SH));
            }
        }
    }
    #pragma unroll
    for (int j = 0; j < 4; ++j) {
        float m = -1e30f;
        #pragma unroll
        for (int i = 0; i < 4; ++i)
            #pragma unroll
            for (int r = 0; r < 4; ++r)
                m = fmaxf(m, acc[i][j][r]);
        m = fmaxf(m, __shfl_xor(m, 16, 64));      // reduce over the 4 quarters
        m = fmaxf(m, __shfl_xor(m, 32, 64));
        if (fq == 0) {
            int col = colb + wn + j * 16 + fr;
            atomicMax(&colmax[col], __float_as_int(m + SH));
        }
    }
}

// ---- kernel 3: decode maxes, log-prob, sum. block 0 -> C1 (rowmax), block 1 -> C2 (colmax)
__global__ __launch_bounds__(256) void finalize(const int* __restrict__ rowmax,
                                                const int* __restrict__ colmax,
                                                float* __restrict__ out) {
    const int* src = (blockIdx.x == 0) ? rowmax : colmax;
    int t = threadIdx.x;
    float s = 0.0f;
    for (int i = t; i < NROWS; i += 256) {
        float v = __int_as_float(src[i]) - 2.0f;
        float z = (v - 1.0f) * (1.0f / 0.3f);
        s += -0.5f * z * z + 0.2850342711212634f;   // -(log(0.3)+0.5*log(2*pi))
    }
    #pragma unroll
    for (int off = 32; off; off >>= 1) s += __shfl_xor(s, off, 64);
    __shared__ float wsum[4];
    if ((t & 63) == 0) wsum[t >> 6] = s;
    __syncthreads();
    if (t == 0) out[blockIdx.x] = wsum[0] + wsum[1] + wsum[2] + wsum[3];
}

extern "C" void kernel_launch(void* const* d_in, const int* in_sizes, int n_in,
                              void* d_out, int out_size, void* d_ws, size_t ws_size,
                              hipStream_t stream) {
    const float* ex = (const float*)d_in[0];
    const float* ey = (const float*)d_in[1];
    float* out = (float*)d_out;

    char* ws = (char*)d_ws;
    unsigned char* Aq = (unsigned char*)ws;                                   // 8 MB
    unsigned char* Bq = (unsigned char*)(ws + (size_t)NROWS * D_DIM);         // 8 MB
    int* rowmax = (int*)(ws + (size_t)2 * NROWS * D_DIM);                     // 32 KB
    int* colmax = rowmax + NROWS;                                             // 32 KB

    normalize_rows<<<(2 * NROWS) / 4, 256, 0, stream>>>(ex, ey, Aq, Bq, rowmax);
    gemm_max<<<64 * 64, 256, 0, stream>>>(Aq, Bq, rowmax, colmax);
    finalize<<<2, 256, 0, stream>>>(rowmax, colmax, out);
}